// Round 8
// baseline (825.005 us; speedup 1.0000x reference)
//
#include <hip/hip_runtime.h>
#include <hip/hip_fp16.h>
#include <math.h>

#define NUSER 10000
#define NITEM 30000
#define NN    40000
#define DD    64
#define PLANE ((size_t)NN * DD)

typedef _Float16 hv2 __attribute__((ext_vector_type(2)));
union U2H { unsigned u; hv2 v; __half2 hh; };

#if defined(__has_builtin)
#if __has_builtin(__builtin_amdgcn_fdot2)
#define HAS_FDOT2 1
#endif
#endif

__device__ __forceinline__ float fdot2u(unsigned a, unsigned b, float c) {
#ifdef HAS_FDOT2
    U2H x, y;
    x.u = a;
    y.u = b;
    return __builtin_amdgcn_fdot2(x.v, y.v, c, false);
#else
    U2H x, y;
    x.u = a;
    y.u = b;
    float2 fa = __half22float2(x.hh), fb = __half22float2(y.hh);
    return c + fa.x * fb.x + fa.y * fb.y;
#endif
}

__device__ __forceinline__ float dot8(uint4 a, uint4 b) {
    float d = fdot2u(a.x, b.x, 0.f);
    d = fdot2u(a.y, b.y, d);
    d = fdot2u(a.z, b.z, d);
    d = fdot2u(a.w, b.w, d);
    return d;
}

__device__ __forceinline__ __half2 uh(unsigned u) { U2H x; x.u = u; return x.hh; }
__device__ __forceinline__ unsigned hu(__half2 h) { U2H x; x.hh = h; return x.u; }
__device__ __forceinline__ __half2 h2rx(__half2 v, int m) {
    return __hadd2(v, uh((unsigned)__shfl_xor((int)hu(v), m, 64)));
}

__device__ __forceinline__ float wsum(float v) {
#pragma unroll
    for (int o = 32; o > 0; o >>= 1) v += __shfl_xor(v, o, 64);
    return v;
}
__device__ __forceinline__ float qsum8(float v) {
    v += __shfl_xor(v, 1, 64);
    v += __shfl_xor(v, 2, 64);
    v += __shfl_xor(v, 4, 64);
    return v;
}
__device__ __forceinline__ float gsum8(float v) {
    v += __shfl_xor(v, 8, 64);
    v += __shfl_xor(v, 16, 64);
    v += __shfl_xor(v, 32, 64);
    return v;
}

// block-balanced node order: [user, item, item, item] repeating
__device__ __forceinline__ int nodeperm(int i) {
    return ((i & 3) == 0) ? (i >> 2) : (NUSER + i - 1 - (i >> 2));
}

// ---------------- CSR build ----------------
__global__ void k_hist(const int* ei, int E2, int E, int* cnt) {
    int i = blockIdx.x * blockDim.x + threadIdx.x;
    if (i >= E2) return;
    int d = (i < E) ? ei[E + i] : ei[i - E];
    atomicAdd(&cnt[d], 1);
}

__global__ void k_bsum(const int* __restrict__ cnt, int* __restrict__ bsum, int n, int chunk) {
    __shared__ int wsh[4];
    int b = blockIdx.x, tid = threadIdx.x;
    int base = b * chunk, end = min(n, base + chunk);
    int s = 0;
    for (int i = base + tid; i < end; i += 256) s += cnt[i];
#pragma unroll
    for (int o = 32; o > 0; o >>= 1) s += __shfl_xor(s, o, 64);
    if ((tid & 63) == 0) wsh[tid >> 6] = s;
    __syncthreads();
    if (tid == 0) bsum[b] = wsh[0] + wsh[1] + wsh[2] + wsh[3];
}

__global__ void k_bscan(int* bsum, int nb, int* rp_end) {
    int lane = threadIdx.x;
    int v = (lane < nb) ? bsum[lane] : 0;
    int orig = v;
#pragma unroll
    for (int o = 1; o < 64; o <<= 1) {
        int y = __shfl_up(v, o, 64);
        if (lane >= o) v += y;
    }
    if (lane < nb) bsum[lane] = v - orig;
    if (lane == 63) *rp_end = v;
}

__global__ void k_apply(const int* __restrict__ cnt, const int* __restrict__ boff,
                        int* __restrict__ rp, int n, int chunk) {
    __shared__ int buf[256];
    __shared__ int csh;
    int b = blockIdx.x, tid = threadIdx.x;
    int base = b * chunk, end = min(n, base + chunk);
    int carry = boff[b];
    for (int t0 = base; t0 < end; t0 += 256) {
        int i = t0 + tid;
        int v = (i < end) ? cnt[i] : 0;
        int x = v;
        buf[tid] = x;
        __syncthreads();
        for (int o = 1; o < 256; o <<= 1) {
            int y = (tid >= o) ? buf[tid - o] : 0;
            __syncthreads();
            x += y;
            buf[tid] = x;
            __syncthreads();
        }
        if (i < end) rp[i] = carry + x - v;
        __syncthreads();
        if (tid == 255) csh = carry + x;
        __syncthreads();
        carry = csh;
    }
}

// scatter; also records undirected edge id per CSR slot
__global__ void k_scatter(const int* ei, int E2, int E, const int* rp, int* fill, int* col,
                          int* ep) {
    int i = blockIdx.x * blockDim.x + threadIdx.x;
    if (i >= E2) return;
    int j = (i < E) ? i : i - E;
    int s = (i < E) ? ei[j] : ei[E + j];
    int d = (i < E) ? ei[E + j] : ei[j];
    int pos = rp[d] + atomicAdd(&fill[d], 1);
    col[pos] = s;
    ep[pos] = j;
}

// ---------------- node prep (planar fp16 tables) ----------------
__global__ void k_prep_pref(const float* __restrict__ pv, const float* __restrict__ pa,
                            const float* __restrict__ pt, __half* __restrict__ M) {
    int t = blockIdx.x * blockDim.x + threadIdx.x;
    int w = t >> 6, lane = t & 63, nw = (gridDim.x * blockDim.x) >> 6;
    for (int r = w; r < NUSER; r += nw) {
        float a = pv[(size_t)r * DD + lane];
        float b = pa[(size_t)r * DD + lane];
        float c = pt[(size_t)r * DD + lane];
        float sa = a * a, sb = b * b, sc = c * c;
#pragma unroll
        for (int o = 32; o > 0; o >>= 1) {
            sa += __shfl_xor(sa, o, 64);
            sb += __shfl_xor(sb, o, 64);
            sc += __shfl_xor(sc, o, 64);
        }
        size_t base = (size_t)r * DD + lane;
        M[base] = __float2half(a / fmaxf(sqrtf(sa), 1e-12f));
        M[base + PLANE] = __float2half(b / fmaxf(sqrtf(sb), 1e-12f));
        M[base + 2 * PLANE] = __float2half(c / fmaxf(sqrtf(sc), 1e-12f));
    }
}

template <int K>
__global__ void k_mlp(const float* __restrict__ feat, const float* __restrict__ W,
                      const float* __restrict__ bias, __half* __restrict__ Mplane) {
    constexpr int K4 = K / 4;
    __shared__ float4 Wl[K4][DD];
    __shared__ float4 rbuf[4][2][K4];
    int t = threadIdx.x, wib = t >> 6, lane = t & 63;
    for (int i = t; i < DD * K4; i += 256) {
        int c = i / K4, k4 = i - c * K4;
        Wl[k4][c] = *(const float4*)(W + (size_t)c * K + k4 * 4);
    }
    __syncthreads();
    float b = bias[lane];
    const int stride = gridDim.x * 4;
    int r = blockIdx.x * 4 + wib;
    float4 v = {0.f, 0.f, 0.f, 0.f};
    if (r < NITEM && lane < K4) v = *(const float4*)(feat + (size_t)r * K + lane * 4);
    int cur = 0;
    for (; r < NITEM; r += stride) {
        if (lane < K4) rbuf[wib][cur][lane] = v;
        int rn = r + stride;
        if (rn < NITEM && lane < K4) v = *(const float4*)(feat + (size_t)rn * K + lane * 4);
        asm volatile("s_waitcnt lgkmcnt(0)" ::: "memory");
        float acc = b;
#pragma unroll
        for (int k4 = 0; k4 < K4; k4++) {
            float4 x4 = rbuf[wib][cur][k4];
            float4 w4 = Wl[k4][lane];
            acc += x4.x * w4.x + x4.y * w4.y + x4.z * w4.z + x4.w * w4.w;
        }
        float h = acc > 0.f ? acc : 0.01f * acc;
        float n = sqrtf(wsum(h * h));
        Mplane[(size_t)(NUSER + r) * DD + lane] = __float2half(h / fmaxf(n, 1e-12f));
        cur ^= 1;
    }
}

// ---------------- GEMM: fp16 planar in -> fp16 planar out, blockIdx.y = mo ----------------
__global__ void k_gemm_h3(const __half* __restrict__ x3, const float* __restrict__ W3,
                          __half* __restrict__ o3) {
    __shared__ float rowbuf[4][DD];
    int mo = blockIdx.y;
    const __half* x = x3 + (size_t)mo * PLANE;
    __half* o = o3 + (size_t)mo * PLANE;
    const float* W = W3 + (size_t)mo * 4096;
    int t = threadIdx.x, wib = t >> 6, lane = t & 63;
    float Wc[DD];
#pragma unroll
    for (int k = 0; k < DD; k++) Wc[k] = W[k * DD + lane];
    for (int r = blockIdx.x * 4 + wib; r < NN; r += gridDim.x * 4) {
        size_t idx = (size_t)r * DD + lane;
        rowbuf[wib][lane] = __half2float(x[idx]);
        asm volatile("s_waitcnt lgkmcnt(0)" ::: "memory");
        float acc = 0.f;
#pragma unroll
        for (int k4 = 0; k4 < DD / 4; k4++) {
            float4 xq = *(const float4*)&rowbuf[wib][k4 * 4];
            acc += xq.x * Wc[k4 * 4] + xq.y * Wc[k4 * 4 + 1] + xq.z * Wc[k4 * 4 + 2] +
                   xq.w * Wc[k4 * 4 + 3];
        }
        o[idx] = __float2half(acc);
    }
}

__global__ void k_gemm_f2(const float* __restrict__ x, const float* __restrict__ W2,
                          __half* __restrict__ o2) {
    __shared__ float rowbuf[4][DD];
    int mo = blockIdx.y;
    const float* W = W2 + (size_t)mo * 4096;
    int t = threadIdx.x, wib = t >> 6, lane = t & 63;
    float Wc[DD];
#pragma unroll
    for (int k = 0; k < DD; k++) Wc[k] = W[k * DD + lane];
    for (int r = blockIdx.x * 4 + wib; r < NN; r += gridDim.x * 4) {
        rowbuf[wib][lane] = x[(size_t)r * DD + lane];
        asm volatile("s_waitcnt lgkmcnt(0)" ::: "memory");
        float acc = 0.f;
#pragma unroll
        for (int k4 = 0; k4 < DD / 4; k4++) {
            float4 xq = *(const float4*)&rowbuf[wib][k4 * 4];
            acc += xq.x * Wc[k4 * 4] + xq.y * Wc[k4 * 4 + 1] + xq.z * Wc[k4 * 4 + 2] +
                   xq.w * Wc[k4 * 4 + 3];
        }
        o2[((size_t)r * 2 + mo) * DD + lane] = __float2half(acc);
    }
}

__global__ void k_gemm_id(const float* __restrict__ x, const float* __restrict__ W,
                          __half* __restrict__ hout, float* __restrict__ xnorm) {
    __shared__ float rowbuf[4][DD];
    int t = threadIdx.x, wib = t >> 6, lane = t & 63;
    float Wc[DD];
#pragma unroll
    for (int k = 0; k < DD; k++) Wc[k] = W[k * DD + lane];
    for (int r = blockIdx.x * 4 + wib; r < NN; r += gridDim.x * 4) {
        float xv = x[(size_t)r * DD + lane];
        float n = sqrtf(wsum(xv * xv));
        xv /= fmaxf(n, 1e-12f);
        xnorm[(size_t)r * DD + lane] = xv;
        rowbuf[wib][lane] = xv;
        asm volatile("s_waitcnt lgkmcnt(0)" ::: "memory");
        float acc = 0.f;
#pragma unroll
        for (int k4 = 0; k4 < DD / 4; k4++) {
            float4 xq = *(const float4*)&rowbuf[wib][k4 * 4];
            acc += xq.x * Wc[k4 * 4] + xq.y * Wc[k4 * 4 + 1] + xq.z * Wc[k4 * 4 + 2] +
                   xq.w * Wc[k4 * 4 + 3];
        }
        hout[(size_t)r * DD + lane] = __float2half(acc);
    }
}

// ---------------- edge dots: user side only (scores are symmetric) ----------------
__global__ void k_edgedot_m(const __half* __restrict__ M, const int* __restrict__ rp,
                            const int* __restrict__ col, const int* __restrict__ ep,
                            __half* __restrict__ D) {
    int t = blockIdx.x * blockDim.x + threadIdx.x;
    int wv = t >> 6, lane = t & 63, nw = (gridDim.x * blockDim.x) >> 6;
    int g = lane >> 3, q = lane & 7;
    for (int n = wv; n < NUSER; n += nw) {
        int e0 = rp[n], e1 = rp[n + 1];
        uint4 tr = ((const uint4*)(M + (size_t)n * DD))[q];
        for (int eb = e0 + g; eb < e1; eb += 8) {
            int sn = col[eb];
            uint4 sr = ((const uint4*)(M + (size_t)sn * DD))[q];
            float d = qsum8(dot8(tr, sr));
            if (q == 0) D[ep[eb]] = __float2half(d);
        }
    }
}

__device__ __forceinline__ float gatef(float ssum) {
    float gate = 1.f / (1.f + __expf(-0.5f * ssum));
    return gate > 0.5f ? gate : 1.f;
}

__global__ void k_gatecomb(const __half* __restrict__ Dv, const __half* __restrict__ Da,
                           const __half* __restrict__ Dt, __half* __restrict__ g0,
                           __half* __restrict__ g1, __half* __restrict__ g2, int E) {
    int i = blockIdx.x * blockDim.x + threadIdx.x;
    if (i >= E) return;
    float dv = __half2float(Dv[i]), da = __half2float(Da[i]), dt = __half2float(Dt[i]);
    g0[i] = __float2half(gatef(da + dt));
    g1[i] = __float2half(gatef(dv + dt));
    g2[i] = __float2half(gatef(da + dv));
}

__global__ void k_gateexpand(const int* __restrict__ ep, const __half* __restrict__ g0,
                             const __half* __restrict__ g1, const __half* __restrict__ g2,
                             __half* __restrict__ d0, __half* __restrict__ d1,
                             __half* __restrict__ d2, int E2) {
    int i = blockIdx.x * blockDim.x + threadIdx.x;
    if (i >= E2) return;
    int j = ep[i];
    d0[i] = g0[j];
    d1[i] = g1[j];
    d2[i] = g2[j];
}

// ---------------- per-modality GAT pre ----------------
__global__ void k_gat_pre_m(const __half* __restrict__ h, const __half* __restrict__ gfd,
                            const int* __restrict__ rp, const int* __restrict__ col,
                            __half* __restrict__ xo) {
    int t = blockIdx.x * blockDim.x + threadIdx.x;
    int wv = t >> 6, lane = t & 63, nw = (gridDim.x * blockDim.x) >> 6;
    int g = lane >> 3, q = lane & 7;
    const __half2 z = __floats2half2_rn(0.f, 0.f);
    for (int w0 = wv; w0 < NN; w0 += nw) {
        int n = nodeperm(w0);
        int e0 = rp[n], e1 = rp[n + 1];
        uint4 hd = ((const uint4*)(h + (size_t)n * DD))[q];
        float s = 0.f;
        __half2 a[4] = {z, z, z, z};
        for (int eb = e0 + g; eb < e1; eb += 8) {
            int sn = col[eb];
            uint4 v = ((const uint4*)(h + (size_t)sn * DD))[q];
            float d = qsum8(dot8(hd, v));
            float gt = __half2float(gfd[eb]);
            float sc = d > 0.f ? d : 0.2f * d;
            float p = __expf(sc);
            s += p;
            __half2 pg = __float2half2_rn(p * gt);
            a[0] = __hfma2(pg, uh(v.x), a[0]);
            a[1] = __hfma2(pg, uh(v.y), a[1]);
            a[2] = __hfma2(pg, uh(v.z), a[2]);
            a[3] = __hfma2(pg, uh(v.w), a[3]);
        }
        s = gsum8(s);
#pragma unroll
        for (int j = 0; j < 4; j++) a[j] = h2rx(h2rx(h2rx(a[j], 8), 16), 32);
        float i0 = 1.f / (s + 1e-16f);
        float o[8];
#pragma unroll
        for (int j = 0; j < 4; j++) {
            float2 f = __half22float2(a[j]);
            o[2 * j] = f.x * i0;
            o[2 * j + 1] = f.y * i0;
        }
        float n0 = 0.f;
#pragma unroll
        for (int k = 0; k < 8; k++) n0 += o[k] * o[k];
        n0 = qsum8(n0);
        float r0 = 1.f / fmaxf(sqrtf(n0), 1e-12f);
        if (g == 0) {
            uint4 w_;
            w_.x = hu(__floats2half2_rn(o[0] * r0, o[1] * r0));
            w_.y = hu(__floats2half2_rn(o[2] * r0, o[3] * r0));
            w_.z = hu(__floats2half2_rn(o[4] * r0, o[5] * r0));
            w_.w = hu(__floats2half2_rn(o[6] * r0, o[7] * r0));
            ((uint4*)(xo + (size_t)n * DD))[q] = w_;
        }
    }
}

// ---------------- per-modality GAT ori (residual + l2norm) ----------------
__global__ void k_gat_ori_m(const __half* __restrict__ h, const __half* __restrict__ xin,
                            const int* __restrict__ rp, const int* __restrict__ col,
                            __half* __restrict__ xout, float* __restrict__ fout) {
    int t = blockIdx.x * blockDim.x + threadIdx.x;
    int wv = t >> 6, lane = t & 63, nw = (gridDim.x * blockDim.x) >> 6;
    int g = lane >> 3, q = lane & 7;
    const __half2 z = __floats2half2_rn(0.f, 0.f);
    for (int w0 = wv; w0 < NN; w0 += nw) {
        int n = nodeperm(w0);
        int e0 = rp[n], e1 = rp[n + 1];
        uint4 hd = ((const uint4*)(h + (size_t)n * DD))[q];
        float s = 0.f;
        __half2 a[4] = {z, z, z, z};
        for (int eb = e0 + g; eb < e1; eb += 8) {
            int sn = col[eb];
            uint4 v = ((const uint4*)(h + (size_t)sn * DD))[q];
            float d = qsum8(dot8(hd, v));
            float sc = d > 0.f ? d : 0.2f * d;
            float p = __expf(sc);
            s += p;
            __half2 ph = __float2half2_rn(p);
            a[0] = __hfma2(ph, uh(v.x), a[0]);
            a[1] = __hfma2(ph, uh(v.y), a[1]);
            a[2] = __hfma2(ph, uh(v.z), a[2]);
            a[3] = __hfma2(ph, uh(v.w), a[3]);
        }
        s = gsum8(s);
#pragma unroll
        for (int j = 0; j < 4; j++) a[j] = h2rx(h2rx(h2rx(a[j], 8), 16), 32);
        float i0 = 1.f / (s + 1e-16f);
        uint4 xr = ((const uint4*)(xin + (size_t)n * DD))[q];
        float o[8];
#pragma unroll
        for (int j = 0; j < 4; j++) {
            float2 f = __half22float2(a[j]);
            float2 xf = __half22float2(uh(j == 0 ? xr.x : j == 1 ? xr.y : j == 2 ? xr.z : xr.w));
            o[2 * j] = xf.x + f.x * i0;
            o[2 * j + 1] = xf.y + f.y * i0;
        }
        float n0 = 0.f;
#pragma unroll
        for (int k = 0; k < 8; k++) n0 += o[k] * o[k];
        n0 = qsum8(n0);
        float r0 = 1.f / fmaxf(sqrtf(n0), 1e-12f);
        if (g == 0) {
            if (fout) {
                float* ob = fout + (size_t)n * 256 + q * 8;
                *(float4*)(ob) = make_float4(o[0] * r0, o[1] * r0, o[2] * r0, o[3] * r0);
                *(float4*)(ob + 4) = make_float4(o[4] * r0, o[5] * r0, o[6] * r0, o[7] * r0);
            } else {
                uint4 w_;
                w_.x = hu(__floats2half2_rn(o[0] * r0, o[1] * r0));
                w_.y = hu(__floats2half2_rn(o[2] * r0, o[3] * r0));
                w_.z = hu(__floats2half2_rn(o[4] * r0, o[5] * r0));
                w_.w = hu(__floats2half2_rn(o[6] * r0, o[7] * r0));
                ((uint4*)(xout + (size_t)n * DD))[q] = w_;
            }
        }
    }
}

// ---------------- GCN ----------------
__global__ void k_gcn1(const __half* __restrict__ h, const int* __restrict__ rp,
                       const int* __restrict__ col, float* __restrict__ out) {
    int t = blockIdx.x * blockDim.x + threadIdx.x;
    int wv = t >> 6, lane = t & 63, nw = (gridDim.x * blockDim.x) >> 6;
    int g = lane >> 3, q = lane & 7;
    const __half2 z = __floats2half2_rn(0.f, 0.f);
    for (int w0 = wv; w0 < NN; w0 += nw) {
        int n = nodeperm(w0);
        int e0 = rp[n], e1 = rp[n + 1];
        __half2 a[4] = {z, z, z, z};
        for (int eb = e0 + g; eb < e1; eb += 8) {
            int sn = col[eb];
            uint4 v = ((const uint4*)(h + (size_t)sn * DD))[q];
            a[0] = __hadd2(a[0], uh(v.x));
            a[1] = __hadd2(a[1], uh(v.y));
            a[2] = __hadd2(a[2], uh(v.z));
            a[3] = __hadd2(a[3], uh(v.w));
        }
#pragma unroll
        for (int j = 0; j < 4; j++) a[j] = h2rx(h2rx(h2rx(a[j], 8), 16), 32);
        if (g == 0) {
            float o[8];
#pragma unroll
            for (int j = 0; j < 4; j++) {
                float2 f = __half22float2(a[j]);
                o[2 * j] = f.x > 0.f ? f.x : 0.01f * f.x;
                o[2 * j + 1] = f.y > 0.f ? f.y : 0.01f * f.y;
            }
            float* ob = out + (size_t)n * DD + q * 8;
            *(float4*)(ob) = make_float4(o[0], o[1], o[2], o[3]);
            *(float4*)(ob + 4) = make_float4(o[4], o[5], o[6], o[7]);
        }
    }
}

__global__ void k_gcn_final2(const __half* __restrict__ gp, const int* __restrict__ rp,
                             const int* __restrict__ col, const float* __restrict__ x0,
                             const float* __restrict__ h1, float* __restrict__ out) {
    int t = blockIdx.x * blockDim.x + threadIdx.x;
    int wv = t >> 6, lane = t & 63, nw = (gridDim.x * blockDim.x) >> 6;
    int g = lane >> 3, q = lane & 7;
    const __half2 z = __floats2half2_rn(0.f, 0.f);
    for (int w0 = wv; w0 < NN; w0 += nw) {
        int n = nodeperm(w0);
        int e0 = rp[n], e1 = rp[n + 1];
        __half2 aA[4] = {z, z, z, z}, aB[4] = {z, z, z, z};
        for (int eb = e0 + g; eb < e1; eb += 8) {
            int sn = col[eb];
            const uint4* base = (const uint4*)(gp + (size_t)sn * 128);
            uint4 vA = base[q], vB = base[q + 8];
            aA[0] = __hadd2(aA[0], uh(vA.x));
            aA[1] = __hadd2(aA[1], uh(vA.y));
            aA[2] = __hadd2(aA[2], uh(vA.z));
            aA[3] = __hadd2(aA[3], uh(vA.w));
            aB[0] = __hadd2(aB[0], uh(vB.x));
            aB[1] = __hadd2(aB[1], uh(vB.y));
            aB[2] = __hadd2(aB[2], uh(vB.z));
            aB[3] = __hadd2(aB[3], uh(vB.w));
        }
#pragma unroll
        for (int j = 0; j < 4; j++) {
            aA[j] = h2rx(h2rx(h2rx(aA[j], 8), 16), 32);
            aB[j] = h2rx(h2rx(h2rx(aB[j], 8), 16), 32);
        }
        if (g == 0) {
            const float* p0 = x0 + (size_t)n * DD + q * 8;
            const float* p1 = h1 + (size_t)n * DD + q * 8;
            float4 v0a = *(const float4*)(p0), v0b = *(const float4*)(p0 + 4);
            float4 v1a = *(const float4*)(p1), v1b = *(const float4*)(p1 + 4);
            float o[8];
#pragma unroll
            for (int j = 0; j < 4; j++) {
                float2 fA = __half22float2(aA[j]);
                float2 fB = __half22float2(aB[j]);
                float h2x = fA.x > 0.f ? fA.x : 0.01f * fA.x;
                float h2y = fA.y > 0.f ? fA.y : 0.01f * fA.y;
                o[2 * j] = h2x + fB.x;
                o[2 * j + 1] = h2y + fB.y;
            }
            float* ob = out + (size_t)n * 256 + q * 8;
            *(float4*)(ob) = make_float4(o[0] + v0a.x + v1a.x, o[1] + v0a.y + v1a.y,
                                         o[2] + v0a.z + v1a.z, o[3] + v0a.w + v1a.w);
            *(float4*)(ob + 4) = make_float4(o[4] + v0b.x + v1b.x, o[5] + v0b.y + v1b.y,
                                             o[6] + v0b.z + v1b.z, o[7] + v0b.w + v1b.w);
        }
    }
}

extern "C" void kernel_launch(void* const* d_in, const int* in_sizes, int n_in,
                              void* d_out, int out_size, void* d_ws, size_t ws_size,
                              hipStream_t stream) {
    const int* ei       = (const int*)d_in[0];
    const float* v_feat = (const float*)d_in[1];
    const float* a_feat = (const float*)d_in[2];
    const float* t_feat = (const float*)d_in[3];
    const float* pref_v = (const float*)d_in[4];
    const float* pref_a = (const float*)d_in[5];
    const float* pref_t = (const float*)d_in[6];
    const float* mlp_v_w = (const float*)d_in[7];
    const float* mlp_v_b = (const float*)d_in[8];
    const float* mlp_a_w = (const float*)d_in[9];
    const float* mlp_a_b = (const float*)d_in[10];
    const float* mlp_t_w = (const float*)d_in[11];
    const float* mlp_t_b = (const float*)d_in[12];
    const float* pre_w  = (const float*)d_in[13];
    const float* ori_w  = (const float*)d_in[14];
    const float* gcn_w  = (const float*)d_in[15];
    const float* id_emb = (const float*)d_in[16];
    float* out = (float*)d_out;

    const int E2 = in_sizes[0];
    const int E  = E2 / 2;

    char* w = (char*)d_ws;
    auto alloc = [&](size_t bytes) -> void* {
        void* p = (void*)w;
        w += (bytes + 255) & ~(size_t)255;
        return p;
    };
    int* cnt  = (int*)alloc((size_t)NN * 4);
    int* rp   = (int*)alloc((size_t)(NN + 1) * 4);
    int* bsum = (int*)alloc(256);
    int* col  = (int*)alloc((size_t)E2 * 4);
    int* ep   = (int*)alloc((size_t)E2 * 4);
    __half* Mh  = (__half*)alloc(3 * PLANE * 2);   // planar [3][NN][64]
    __half* hb  = (__half*)alloc(3 * PLANE * 2);   // planar
    __half* x3h = (__half*)alloc(3 * PLANE * 2);   // planar
    __half* Dm  = (__half*)alloc((size_t)3 * E * 2);   // dots per modality (undirected)
    __half* gfp = (__half*)alloc((size_t)3 * E * 2);   // gates per modality (undirected)
    __half* gfd = (__half*)alloc((size_t)3 * E2 * 2);  // gates expanded (directed)
    float* x0f = (float*)alloc(PLANE * 4);
    float* h1f = (float*)alloc(PLANE * 4);

    __half* g1 = hb;
    __half* gpair = hb + PLANE;

    // ---- CSR by destination ----
    const int NBLK = 64, CHUNK = (NN + NBLK - 1) / NBLK;
    hipMemsetAsync(cnt, 0, (size_t)NN * 4, stream);
    k_hist<<<(E2 + 255) / 256, 256, 0, stream>>>(ei, E2, E, cnt);
    k_bsum<<<NBLK, 256, 0, stream>>>(cnt, bsum, NN, CHUNK);
    k_bscan<<<1, 64, 0, stream>>>(bsum, NBLK, rp + NN);
    k_apply<<<NBLK, 256, 0, stream>>>(cnt, bsum, rp, NN, CHUNK);
    hipMemsetAsync(cnt, 0, (size_t)NN * 4, stream);
    k_scatter<<<(E2 + 255) / 256, 256, 0, stream>>>(ei, E2, E, rp, cnt, col, ep);

    // ---- node tables (planar fp16) ----
    k_prep_pref<<<640, 256, 0, stream>>>(pref_v, pref_a, pref_t, Mh);
    k_mlp<128><<<1024, 256, 0, stream>>>(v_feat, mlp_v_w, mlp_v_b, Mh);
    k_mlp<128><<<1024, 256, 0, stream>>>(a_feat, mlp_a_w, mlp_a_b, Mh + PLANE);
    k_mlp<100><<<1024, 256, 0, stream>>>(t_feat, mlp_t_w, mlp_t_b, Mh + 2 * PLANE);

    const int GB = (NN + 3) / 4;
    const int UB = (NUSER + 3) / 4;

    // ---- cross-modal gates: user-side dots (symmetric), combine, expand ----
    k_edgedot_m<<<UB, 256, 0, stream>>>(Mh, rp, col, ep, Dm);
    k_edgedot_m<<<UB, 256, 0, stream>>>(Mh + PLANE, rp, col, ep, Dm + E);
    k_edgedot_m<<<UB, 256, 0, stream>>>(Mh + 2 * PLANE, rp, col, ep, Dm + 2 * (size_t)E);
    k_gatecomb<<<(E + 255) / 256, 256, 0, stream>>>(Dm, Dm + E, Dm + 2 * (size_t)E, gfp,
                                                    gfp + E, gfp + 2 * (size_t)E, E);
    k_gateexpand<<<(E2 + 255) / 256, 256, 0, stream>>>(ep, gfp, gfp + E, gfp + 2 * (size_t)E,
                                                       gfd, gfd + E2, gfd + 2 * (size_t)E2, E2);

    // ---- 3-modality chains (per-modality passes for L2 locality) ----
    dim3 g3(1280, 3);
    k_gemm_h3<<<g3, 256, 0, stream>>>(Mh, pre_w, hb);
    for (int mo = 0; mo < 3; mo++)
        k_gat_pre_m<<<GB, 256, 0, stream>>>(hb + (size_t)mo * PLANE, gfd + (size_t)mo * E2, rp,
                                            col, x3h + (size_t)mo * PLANE);
    for (int it = 0; it < 3; it++) {
        k_gemm_h3<<<g3, 256, 0, stream>>>(x3h, ori_w, hb);
        for (int mo = 0; mo < 3; mo++) {
            __half* hp = hb + (size_t)mo * PLANE;
            __half* xp = x3h + (size_t)mo * PLANE;
            if (it < 2)
                k_gat_ori_m<<<GB, 256, 0, stream>>>(hp, xp, rp, col, xp, nullptr);
            else
                k_gat_ori_m<<<GB, 256, 0, stream>>>(hp, xp, rp, col, nullptr,
                                                    out + 64 + mo * 64);
        }
    }

    // ---- real_gcn ----
    k_gemm_id<<<1280, 256, 0, stream>>>(id_emb, gcn_w, g1, x0f);
    k_gcn1<<<GB, 256, 0, stream>>>(g1, rp, col, h1f);
    dim3 g2(1280, 2);
    k_gemm_f2<<<g2, 256, 0, stream>>>(h1f, gcn_w + 4096, gpair);
    k_gcn_final2<<<GB, 256, 0, stream>>>(gpair, rp, col, x0f, h1f, out);
}

// Round 9
// 554.166 us; speedup vs baseline: 1.4887x; 1.4887x over previous
//
#include <hip/hip_runtime.h>
#include <hip/hip_fp16.h>
#include <math.h>

#define NUSER 10000
#define NITEM 30000
#define NN    40000
#define DD    64
#define PLANE ((size_t)NN * DD)

typedef _Float16 hv2 __attribute__((ext_vector_type(2)));
typedef _Float16 half8v __attribute__((ext_vector_type(8)));
typedef float float4v __attribute__((ext_vector_type(4)));
union U2H { unsigned u; hv2 v; __half2 hh; };

#if defined(__has_builtin)
#if __has_builtin(__builtin_amdgcn_fdot2)
#define HAS_FDOT2 1
#endif
#endif

__device__ __forceinline__ float fdot2u(unsigned a, unsigned b, float c) {
#ifdef HAS_FDOT2
    U2H x, y;
    x.u = a;
    y.u = b;
    return __builtin_amdgcn_fdot2(x.v, y.v, c, false);
#else
    U2H x, y;
    x.u = a;
    y.u = b;
    float2 fa = __half22float2(x.hh), fb = __half22float2(y.hh);
    return c + fa.x * fb.x + fa.y * fb.y;
#endif
}

__device__ __forceinline__ float dot8(uint4 a, uint4 b) {
    float d = fdot2u(a.x, b.x, 0.f);
    d = fdot2u(a.y, b.y, d);
    d = fdot2u(a.z, b.z, d);
    d = fdot2u(a.w, b.w, d);
    return d;
}

__device__ __forceinline__ __half2 uh(unsigned u) { U2H x; x.u = u; return x.hh; }
__device__ __forceinline__ unsigned hu(__half2 h) { U2H x; x.hh = h; return x.u; }
__device__ __forceinline__ __half2 h2rx(__half2 v, int m) {
    return __hadd2(v, uh((unsigned)__shfl_xor((int)hu(v), m, 64)));
}

__device__ __forceinline__ float wsum(float v) {
#pragma unroll
    for (int o = 32; o > 0; o >>= 1) v += __shfl_xor(v, o, 64);
    return v;
}
__device__ __forceinline__ float qsum8(float v) {
    v += __shfl_xor(v, 1, 64);
    v += __shfl_xor(v, 2, 64);
    v += __shfl_xor(v, 4, 64);
    return v;
}
__device__ __forceinline__ float gsum8(float v) {
    v += __shfl_xor(v, 8, 64);
    v += __shfl_xor(v, 16, 64);
    v += __shfl_xor(v, 32, 64);
    return v;
}

// block-balanced node order: [user, item, item, item] repeating
__device__ __forceinline__ int nodeperm(int i) {
    return ((i & 3) == 0) ? (i >> 2) : (NUSER + i - 1 - (i >> 2));
}

// ---------------- CSR build ----------------
// hist also records each edge's position within its destination bucket
__global__ void k_hist(const int* ei, int E2, int E, int* cnt, int* posw) {
    int i = blockIdx.x * blockDim.x + threadIdx.x;
    if (i >= E2) return;
    int d = (i < E) ? ei[E + i] : ei[i - E];
    posw[i] = atomicAdd(&cnt[d], 1);
}

__global__ void k_bsum(const int* __restrict__ cnt, int* __restrict__ bsum, int n, int chunk) {
    __shared__ int wsh[4];
    int b = blockIdx.x, tid = threadIdx.x;
    int base = b * chunk, end = min(n, base + chunk);
    int s = 0;
    for (int i = base + tid; i < end; i += 256) s += cnt[i];
#pragma unroll
    for (int o = 32; o > 0; o >>= 1) s += __shfl_xor(s, o, 64);
    if ((tid & 63) == 0) wsh[tid >> 6] = s;
    __syncthreads();
    if (tid == 0) bsum[b] = wsh[0] + wsh[1] + wsh[2] + wsh[3];
}

__global__ void k_bscan(int* bsum, int nb, int* rp_end) {
    int lane = threadIdx.x;
    int v = (lane < nb) ? bsum[lane] : 0;
    int orig = v;
#pragma unroll
    for (int o = 1; o < 64; o <<= 1) {
        int y = __shfl_up(v, o, 64);
        if (lane >= o) v += y;
    }
    if (lane < nb) bsum[lane] = v - orig;
    if (lane == 63) *rp_end = v;
}

__global__ void k_apply(const int* __restrict__ cnt, const int* __restrict__ boff,
                        int* __restrict__ rp, int n, int chunk) {
    __shared__ int buf[256];
    __shared__ int csh;
    int b = blockIdx.x, tid = threadIdx.x;
    int base = b * chunk, end = min(n, base + chunk);
    int carry = boff[b];
    for (int t0 = base; t0 < end; t0 += 256) {
        int i = t0 + tid;
        int v = (i < end) ? cnt[i] : 0;
        int x = v;
        buf[tid] = x;
        __syncthreads();
        for (int o = 1; o < 256; o <<= 1) {
            int y = (tid >= o) ? buf[tid - o] : 0;
            __syncthreads();
            x += y;
            buf[tid] = x;
            __syncthreads();
        }
        if (i < end) rp[i] = carry + x - v;
        __syncthreads();
        if (tid == 255) csh = carry + x;
        __syncthreads();
        carry = csh;
    }
}

// atomic-free scatter using recorded positions
__global__ void k_scatter(const int* ei, int E2, int E, const int* rp,
                          const int* __restrict__ posw, int* col) {
    int i = blockIdx.x * blockDim.x + threadIdx.x;
    if (i >= E2) return;
    int j = (i < E) ? i : i - E;
    int s = (i < E) ? ei[j] : ei[E + j];
    int d = (i < E) ? ei[E + j] : ei[j];
    col[rp[d] + posw[i]] = s;
}

// ---------------- node prep: 3 prefs -> interleaved fp16 M ----------------
__global__ void k_prep_pref(const float* __restrict__ pv, const float* __restrict__ pa,
                            const float* __restrict__ pt, __half* __restrict__ M) {
    int t = blockIdx.x * blockDim.x + threadIdx.x;
    int w = t >> 6, lane = t & 63, nw = (gridDim.x * blockDim.x) >> 6;
    for (int r = w; r < NUSER; r += nw) {
        float a = pv[(size_t)r * DD + lane];
        float b = pa[(size_t)r * DD + lane];
        float c = pt[(size_t)r * DD + lane];
        float sa = a * a, sb = b * b, sc = c * c;
#pragma unroll
        for (int o = 32; o > 0; o >>= 1) {
            sa += __shfl_xor(sa, o, 64);
            sb += __shfl_xor(sb, o, 64);
            sc += __shfl_xor(sc, o, 64);
        }
        size_t base = (size_t)r * 3 * DD + lane;
        M[base] = __float2half(a / fmaxf(sqrtf(sa), 1e-12f));
        M[base + DD] = __float2half(b / fmaxf(sqrtf(sb), 1e-12f));
        M[base + 2 * DD] = __float2half(c / fmaxf(sqrtf(sc), 1e-12f));
    }
}

template <int K>
__global__ void k_mlp(const float* __restrict__ feat, const float* __restrict__ W,
                      const float* __restrict__ bias, __half* __restrict__ M, int mo) {
    constexpr int K4 = K / 4;
    __shared__ float4 Wl[K4][DD];
    __shared__ float4 rbuf[4][2][K4];
    int t = threadIdx.x, wib = t >> 6, lane = t & 63;
    for (int i = t; i < DD * K4; i += 256) {
        int c = i / K4, k4 = i - c * K4;
        Wl[k4][c] = *(const float4*)(W + (size_t)c * K + k4 * 4);
    }
    __syncthreads();
    float b = bias[lane];
    const int stride = gridDim.x * 4;
    int r = blockIdx.x * 4 + wib;
    float4 v = {0.f, 0.f, 0.f, 0.f};
    if (r < NITEM && lane < K4) v = *(const float4*)(feat + (size_t)r * K + lane * 4);
    int cur = 0;
    for (; r < NITEM; r += stride) {
        if (lane < K4) rbuf[wib][cur][lane] = v;
        int rn = r + stride;
        if (rn < NITEM && lane < K4) v = *(const float4*)(feat + (size_t)rn * K + lane * 4);
        asm volatile("s_waitcnt lgkmcnt(0)" ::: "memory");
        float acc = b;
#pragma unroll
        for (int k4 = 0; k4 < K4; k4++) {
            float4 x4 = rbuf[wib][cur][k4];
            float4 w4 = Wl[k4][lane];
            acc += x4.x * w4.x + x4.y * w4.y + x4.z * w4.z + x4.w * w4.w;
        }
        float h = acc > 0.f ? acc : 0.01f * acc;
        float n = sqrtf(wsum(h * h));
        M[((size_t)(NUSER + r) * 3 + mo) * DD + lane] = __float2half(h / fmaxf(n, 1e-12f));
        cur ^= 1;
    }
}

// ---------------- MFMA GEMM: fp16 interleaved-3 in -> fp16 interleaved-3 out ----------------
// out[n, mo, c] = sum_k x[n, mo, k] * W[mo][k][c]; per wave: 16 rows x 64 cols,
// 4 col-tiles x 2 k-halves = 8 x mfma_f32_16x16x32_f16.
__global__ void k_gemm_mfma(const __half* __restrict__ x3, const float* __restrict__ W3,
                            __half* __restrict__ o3) {
    int mo = blockIdx.y;
    const float* W = W3 + (size_t)mo * 4096;
    int t = threadIdx.x, wv = t >> 6, lane = t & 63;
    int lr = lane & 15, lg = lane >> 4;  // lr: row/col-in-tile, lg: 0..3
    // B frags: b[ct][kh][i] = W[kh*32 + lg*8 + i][ct*16 + lr]
    half8v b[4][2];
#pragma unroll
    for (int ct = 0; ct < 4; ct++)
#pragma unroll
        for (int kh = 0; kh < 2; kh++)
#pragma unroll
            for (int i = 0; i < 8; i++)
                b[ct][kh][i] = (_Float16)W[(kh * 32 + lg * 8 + i) * 64 + ct * 16 + lr];
    const int NT = NN / 16;  // 2500 row-tiles
    for (int rt = blockIdx.x * 4 + wv; rt < NT; rt += gridDim.x * 4) {
        const __half* xr = x3 + ((size_t)(rt * 16 + lr) * 3 + mo) * DD + lg * 8;
        half8v a0 = *(const half8v*)xr;         // k = lg*8 .. lg*8+7
        half8v a1 = *(const half8v*)(xr + 32);  // k = 32 + lg*8 ..
        float4v acc0 = {0.f, 0.f, 0.f, 0.f}, acc1 = acc0, acc2 = acc0, acc3 = acc0;
        acc0 = __builtin_amdgcn_mfma_f32_16x16x32_f16(a0, b[0][0], acc0, 0, 0, 0);
        acc1 = __builtin_amdgcn_mfma_f32_16x16x32_f16(a0, b[1][0], acc1, 0, 0, 0);
        acc2 = __builtin_amdgcn_mfma_f32_16x16x32_f16(a0, b[2][0], acc2, 0, 0, 0);
        acc3 = __builtin_amdgcn_mfma_f32_16x16x32_f16(a0, b[3][0], acc3, 0, 0, 0);
        acc0 = __builtin_amdgcn_mfma_f32_16x16x32_f16(a1, b[0][1], acc0, 0, 0, 0);
        acc1 = __builtin_amdgcn_mfma_f32_16x16x32_f16(a1, b[1][1], acc1, 0, 0, 0);
        acc2 = __builtin_amdgcn_mfma_f32_16x16x32_f16(a1, b[2][1], acc2, 0, 0, 0);
        acc3 = __builtin_amdgcn_mfma_f32_16x16x32_f16(a1, b[3][1], acc3, 0, 0, 0);
        // C/D: col = lr, row = lg*4 + i
#pragma unroll
        for (int i = 0; i < 4; i++) {
            size_t rbase = ((size_t)(rt * 16 + lg * 4 + i) * 3 + mo) * DD + lr;
            o3[rbase] = __float2half(acc0[i]);
            o3[rbase + 16] = __float2half(acc1[i]);
            o3[rbase + 32] = __float2half(acc2[i]);
            o3[rbase + 48] = __float2half(acc3[i]);
        }
    }
}

// fp32 flat in -> fp16 interleaved-2 out (gcn W1/W2 pair)
__global__ void k_gemm_f2(const float* __restrict__ x, const float* __restrict__ W2,
                          __half* __restrict__ o2) {
    __shared__ float rowbuf[4][DD];
    int mo = blockIdx.y;
    const float* W = W2 + (size_t)mo * 4096;
    int t = threadIdx.x, wib = t >> 6, lane = t & 63;
    float Wc[DD];
#pragma unroll
    for (int k = 0; k < DD; k++) Wc[k] = W[k * DD + lane];
    for (int r = blockIdx.x * 4 + wib; r < NN; r += gridDim.x * 4) {
        rowbuf[wib][lane] = x[(size_t)r * DD + lane];
        asm volatile("s_waitcnt lgkmcnt(0)" ::: "memory");
        float acc = 0.f;
#pragma unroll
        for (int k4 = 0; k4 < DD / 4; k4++) {
            float4 xq = *(const float4*)&rowbuf[wib][k4 * 4];
            acc += xq.x * Wc[k4 * 4] + xq.y * Wc[k4 * 4 + 1] + xq.z * Wc[k4 * 4 + 2] +
                   xq.w * Wc[k4 * 4 + 3];
        }
        o2[((size_t)r * 2 + mo) * DD + lane] = __float2half(acc);
    }
}

__global__ void k_gemm_id(const float* __restrict__ x, const float* __restrict__ W,
                          __half* __restrict__ hout, float* __restrict__ xnorm) {
    __shared__ float rowbuf[4][DD];
    int t = threadIdx.x, wib = t >> 6, lane = t & 63;
    float Wc[DD];
#pragma unroll
    for (int k = 0; k < DD; k++) Wc[k] = W[k * DD + lane];
    for (int r = blockIdx.x * 4 + wib; r < NN; r += gridDim.x * 4) {
        float xv = x[(size_t)r * DD + lane];
        float n = sqrtf(wsum(xv * xv));
        xv /= fmaxf(n, 1e-12f);
        xnorm[(size_t)r * DD + lane] = xv;
        rowbuf[wib][lane] = xv;
        asm volatile("s_waitcnt lgkmcnt(0)" ::: "memory");
        float acc = 0.f;
#pragma unroll
        for (int k4 = 0; k4 < DD / 4; k4++) {
            float4 xq = *(const float4*)&rowbuf[wib][k4 * 4];
            acc += xq.x * Wc[k4 * 4] + xq.y * Wc[k4 * 4 + 1] + xq.z * Wc[k4 * 4 + 2] +
                   xq.w * Wc[k4 * 4 + 3];
        }
        hout[(size_t)r * DD + lane] = __float2half(acc);
    }
}

// ---------------- edge gate factors ----------------
__device__ __forceinline__ float gatef(float ssum) {
    float gate = 1.f / (1.f + __expf(-0.5f * ssum));
    return gate > 0.5f ? gate : 1.f;
}

__global__ void k_edgedot3(const __half* __restrict__ M, const int* __restrict__ rp,
                           const int* __restrict__ col, __half* __restrict__ gf4) {
    int t = blockIdx.x * blockDim.x + threadIdx.x;
    int wv = t >> 6, lane = t & 63, nw = (gridDim.x * blockDim.x) >> 6;
    int g = lane >> 3, q = lane & 7;
    for (int w0 = wv; w0 < NN; w0 += nw) {
        int n = nodeperm(w0);
        int e0 = rp[n], e1 = rp[n + 1];
        if (e0 == e1) continue;
        const uint4* trow = (const uint4*)(M + (size_t)n * 192);
        uint4 tv = trow[q], ta = trow[q + 8], tt = trow[q + 16];
        for (int eb = e0 + g; eb < e1; eb += 8) {
            int sn = col[eb];
            const uint4* srow = (const uint4*)(M + (size_t)sn * 192);
            uint4 sv = srow[q], sa = srow[q + 8], st = srow[q + 16];
            float dv = dot8(tv, sv), da = dot8(ta, sa), dt = dot8(tt, st);
            dv = qsum8(dv);
            da = qsum8(da);
            dt = qsum8(dt);
            if (q == 0) {
                U2H p01, p2;
                p01.hh = __floats2half2_rn(gatef(da + dt), gatef(dv + dt));
                p2.hh = __floats2half2_rn(gatef(da + dv), 0.f);
                *(uint2*)(gf4 + (size_t)eb * 4) = make_uint2(p01.u, p2.u);
            }
        }
    }
}

// ---------------- fused 3-modality GAT pre (fp16 acc, gate folded) ----------------
__global__ void k_gat_pre3(const __half* __restrict__ h3, const __half* __restrict__ gf4,
                           const int* __restrict__ rp, const int* __restrict__ col,
                           __half* __restrict__ x3h) {
    int t = blockIdx.x * blockDim.x + threadIdx.x;
    int wv = t >> 6, lane = t & 63, nw = (gridDim.x * blockDim.x) >> 6;
    int g = lane >> 3, q = lane & 7;
    const __half2 z = __floats2half2_rn(0.f, 0.f);
    for (int w0 = wv; w0 < NN; w0 += nw) {
        int n = nodeperm(w0);
        int e0 = rp[n], e1 = rp[n + 1];
        const uint4* hrow = (const uint4*)(h3 + (size_t)n * 192);
        uint4 hd0 = hrow[q], hd1 = hrow[q + 8], hd2 = hrow[q + 16];
        float s0 = 0.f, s1 = 0.f, s2 = 0.f;
        __half2 a0[4] = {z, z, z, z}, a1[4] = {z, z, z, z}, a2[4] = {z, z, z, z};
        for (int eb = e0 + g; eb < e1; eb += 8) {
            int sn = col[eb];
            const uint4* srow = (const uint4*)(h3 + (size_t)sn * 192);
            uint4 v0 = srow[q], v1 = srow[q + 8], v2 = srow[q + 16];
            uint2 gv = *(const uint2*)(gf4 + (size_t)eb * 4);
            float d0 = dot8(hd0, v0), d1 = dot8(hd1, v1), d2 = dot8(hd2, v2);
            d0 = qsum8(d0);
            d1 = qsum8(d1);
            d2 = qsum8(d2);
            float2 g01 = __half22float2(uh(gv.x));
            float g2 = __half22float2(uh(gv.y)).x;
            float sc0 = d0 > 0.f ? d0 : 0.2f * d0;
            float sc1 = d1 > 0.f ? d1 : 0.2f * d1;
            float sc2 = d2 > 0.f ? d2 : 0.2f * d2;
            float p0 = __expf(sc0), p1 = __expf(sc1), p2 = __expf(sc2);
            s0 += p0;
            s1 += p1;
            s2 += p2;
            __half2 ph0 = __float2half2_rn(p0 * g01.x);
            __half2 ph1 = __float2half2_rn(p1 * g01.y);
            __half2 ph2 = __float2half2_rn(p2 * g2);
            a0[0] = __hfma2(ph0, uh(v0.x), a0[0]);
            a0[1] = __hfma2(ph0, uh(v0.y), a0[1]);
            a0[2] = __hfma2(ph0, uh(v0.z), a0[2]);
            a0[3] = __hfma2(ph0, uh(v0.w), a0[3]);
            a1[0] = __hfma2(ph1, uh(v1.x), a1[0]);
            a1[1] = __hfma2(ph1, uh(v1.y), a1[1]);
            a1[2] = __hfma2(ph1, uh(v1.z), a1[2]);
            a1[3] = __hfma2(ph1, uh(v1.w), a1[3]);
            a2[0] = __hfma2(ph2, uh(v2.x), a2[0]);
            a2[1] = __hfma2(ph2, uh(v2.y), a2[1]);
            a2[2] = __hfma2(ph2, uh(v2.z), a2[2]);
            a2[3] = __hfma2(ph2, uh(v2.w), a2[3]);
        }
        s0 = gsum8(s0);
        s1 = gsum8(s1);
        s2 = gsum8(s2);
#pragma unroll
        for (int j = 0; j < 4; j++) {
            a0[j] = h2rx(h2rx(h2rx(a0[j], 8), 16), 32);
            a1[j] = h2rx(h2rx(h2rx(a1[j], 8), 16), 32);
            a2[j] = h2rx(h2rx(h2rx(a2[j], 8), 16), 32);
        }
        float i0 = 1.f / (s0 + 1e-16f), i1 = 1.f / (s1 + 1e-16f), i2 = 1.f / (s2 + 1e-16f);
        float o0[8], o1[8], o2[8];
#pragma unroll
        for (int j = 0; j < 4; j++) {
            float2 f0 = __half22float2(a0[j]);
            float2 f1 = __half22float2(a1[j]);
            float2 f2 = __half22float2(a2[j]);
            o0[2 * j] = f0.x * i0;
            o0[2 * j + 1] = f0.y * i0;
            o1[2 * j] = f1.x * i1;
            o1[2 * j + 1] = f1.y * i1;
            o2[2 * j] = f2.x * i2;
            o2[2 * j + 1] = f2.y * i2;
        }
        float n0 = 0.f, n1 = 0.f, n2 = 0.f;
#pragma unroll
        for (int k = 0; k < 8; k++) {
            n0 += o0[k] * o0[k];
            n1 += o1[k] * o1[k];
            n2 += o2[k] * o2[k];
        }
        n0 = qsum8(n0);
        n1 = qsum8(n1);
        n2 = qsum8(n2);
        float r0 = 1.f / fmaxf(sqrtf(n0), 1e-12f);
        float r1 = 1.f / fmaxf(sqrtf(n1), 1e-12f);
        float r2 = 1.f / fmaxf(sqrtf(n2), 1e-12f);
        if (g == 0) {
            uint4* orow = (uint4*)(x3h + (size_t)n * 192);
            uint4 w0_, w1_, w2_;
            w0_.x = hu(__floats2half2_rn(o0[0] * r0, o0[1] * r0));
            w0_.y = hu(__floats2half2_rn(o0[2] * r0, o0[3] * r0));
            w0_.z = hu(__floats2half2_rn(o0[4] * r0, o0[5] * r0));
            w0_.w = hu(__floats2half2_rn(o0[6] * r0, o0[7] * r0));
            w1_.x = hu(__floats2half2_rn(o1[0] * r1, o1[1] * r1));
            w1_.y = hu(__floats2half2_rn(o1[2] * r1, o1[3] * r1));
            w1_.z = hu(__floats2half2_rn(o1[4] * r1, o1[5] * r1));
            w1_.w = hu(__floats2half2_rn(o1[6] * r1, o1[7] * r1));
            w2_.x = hu(__floats2half2_rn(o2[0] * r2, o2[1] * r2));
            w2_.y = hu(__floats2half2_rn(o2[2] * r2, o2[3] * r2));
            w2_.z = hu(__floats2half2_rn(o2[4] * r2, o2[5] * r2));
            w2_.w = hu(__floats2half2_rn(o2[6] * r2, o2[7] * r2));
            orow[q] = w0_;
            orow[q + 8] = w1_;
            orow[q + 16] = w2_;
        }
    }
}

// ---------------- fused 3-modality GAT ori (residual + l2norm) ----------------
__global__ void k_gat_ori3(const __half* __restrict__ h3, const __half* __restrict__ x3h,
                           const int* __restrict__ rp, const int* __restrict__ col,
                           __half* __restrict__ xout, float* __restrict__ fout) {
    int t = blockIdx.x * blockDim.x + threadIdx.x;
    int wv = t >> 6, lane = t & 63, nw = (gridDim.x * blockDim.x) >> 6;
    int g = lane >> 3, q = lane & 7;
    const __half2 z = __floats2half2_rn(0.f, 0.f);
    for (int w0 = wv; w0 < NN; w0 += nw) {
        int n = nodeperm(w0);
        int e0 = rp[n], e1 = rp[n + 1];
        const uint4* hrow = (const uint4*)(h3 + (size_t)n * 192);
        uint4 hd0 = hrow[q], hd1 = hrow[q + 8], hd2 = hrow[q + 16];
        float s0 = 0.f, s1 = 0.f, s2 = 0.f;
        __half2 a0[4] = {z, z, z, z}, a1[4] = {z, z, z, z}, a2[4] = {z, z, z, z};
        for (int eb = e0 + g; eb < e1; eb += 8) {
            int sn = col[eb];
            const uint4* srow = (const uint4*)(h3 + (size_t)sn * 192);
            uint4 v0 = srow[q], v1 = srow[q + 8], v2 = srow[q + 16];
            float d0 = dot8(hd0, v0), d1 = dot8(hd1, v1), d2 = dot8(hd2, v2);
            d0 = qsum8(d0);
            d1 = qsum8(d1);
            d2 = qsum8(d2);
            float sc0 = d0 > 0.f ? d0 : 0.2f * d0;
            float sc1 = d1 > 0.f ? d1 : 0.2f * d1;
            float sc2 = d2 > 0.f ? d2 : 0.2f * d2;
            float p0 = __expf(sc0), p1 = __expf(sc1), p2 = __expf(sc2);
            s0 += p0;
            s1 += p1;
            s2 += p2;
            __half2 ph0 = __float2half2_rn(p0);
            __half2 ph1 = __float2half2_rn(p1);
            __half2 ph2 = __float2half2_rn(p2);
            a0[0] = __hfma2(ph0, uh(v0.x), a0[0]);
            a0[1] = __hfma2(ph0, uh(v0.y), a0[1]);
            a0[2] = __hfma2(ph0, uh(v0.z), a0[2]);
            a0[3] = __hfma2(ph0, uh(v0.w), a0[3]);
            a1[0] = __hfma2(ph1, uh(v1.x), a1[0]);
            a1[1] = __hfma2(ph1, uh(v1.y), a1[1]);
            a1[2] = __hfma2(ph1, uh(v1.z), a1[2]);
            a1[3] = __hfma2(ph1, uh(v1.w), a1[3]);
            a2[0] = __hfma2(ph2, uh(v2.x), a2[0]);
            a2[1] = __hfma2(ph2, uh(v2.y), a2[1]);
            a2[2] = __hfma2(ph2, uh(v2.z), a2[2]);
            a2[3] = __hfma2(ph2, uh(v2.w), a2[3]);
        }
        s0 = gsum8(s0);
        s1 = gsum8(s1);
        s2 = gsum8(s2);
#pragma unroll
        for (int j = 0; j < 4; j++) {
            a0[j] = h2rx(h2rx(h2rx(a0[j], 8), 16), 32);
            a1[j] = h2rx(h2rx(h2rx(a1[j], 8), 16), 32);
            a2[j] = h2rx(h2rx(h2rx(a2[j], 8), 16), 32);
        }
        float i0 = 1.f / (s0 + 1e-16f), i1 = 1.f / (s1 + 1e-16f), i2 = 1.f / (s2 + 1e-16f);
        const uint4* xrow = (const uint4*)(x3h + (size_t)n * 192);
        uint4 xr0 = xrow[q], xr1 = xrow[q + 8], xr2 = xrow[q + 16];
        float o0[8], o1[8], o2[8];
#pragma unroll
        for (int j = 0; j < 4; j++) {
            float2 f0 = __half22float2(a0[j]);
            float2 f1 = __half22float2(a1[j]);
            float2 f2 = __half22float2(a2[j]);
            float2 xf0 = __half22float2(uh(j == 0 ? xr0.x : j == 1 ? xr0.y : j == 2 ? xr0.z : xr0.w));
            float2 xf1 = __half22float2(uh(j == 0 ? xr1.x : j == 1 ? xr1.y : j == 2 ? xr1.z : xr1.w));
            float2 xf2 = __half22float2(uh(j == 0 ? xr2.x : j == 1 ? xr2.y : j == 2 ? xr2.z : xr2.w));
            o0[2 * j] = xf0.x + f0.x * i0;
            o0[2 * j + 1] = xf0.y + f0.y * i0;
            o1[2 * j] = xf1.x + f1.x * i1;
            o1[2 * j + 1] = xf1.y + f1.y * i1;
            o2[2 * j] = xf2.x + f2.x * i2;
            o2[2 * j + 1] = xf2.y + f2.y * i2;
        }
        float n0 = 0.f, n1 = 0.f, n2 = 0.f;
#pragma unroll
        for (int k = 0; k < 8; k++) {
            n0 += o0[k] * o0[k];
            n1 += o1[k] * o1[k];
            n2 += o2[k] * o2[k];
        }
        n0 = qsum8(n0);
        n1 = qsum8(n1);
        n2 = qsum8(n2);
        float r0 = 1.f / fmaxf(sqrtf(n0), 1e-12f);
        float r1 = 1.f / fmaxf(sqrtf(n1), 1e-12f);
        float r2 = 1.f / fmaxf(sqrtf(n2), 1e-12f);
        if (g == 0) {
            if (fout) {
                float* ob = fout + (size_t)n * 256 + 64 + q * 8;
                float4 wa, wb;
                wa = make_float4(o0[0] * r0, o0[1] * r0, o0[2] * r0, o0[3] * r0);
                wb = make_float4(o0[4] * r0, o0[5] * r0, o0[6] * r0, o0[7] * r0);
                *(float4*)(ob) = wa;
                *(float4*)(ob + 4) = wb;
                wa = make_float4(o1[0] * r1, o1[1] * r1, o1[2] * r1, o1[3] * r1);
                wb = make_float4(o1[4] * r1, o1[5] * r1, o1[6] * r1, o1[7] * r1);
                *(float4*)(ob + 64) = wa;
                *(float4*)(ob + 68) = wb;
                wa = make_float4(o2[0] * r2, o2[1] * r2, o2[2] * r2, o2[3] * r2);
                wb = make_float4(o2[4] * r2, o2[5] * r2, o2[6] * r2, o2[7] * r2);
                *(float4*)(ob + 128) = wa;
                *(float4*)(ob + 132) = wb;
            } else {
                uint4* orow = (uint4*)(xout + (size_t)n * 192);
                uint4 w0_, w1_, w2_;
                w0_.x = hu(__floats2half2_rn(o0[0] * r0, o0[1] * r0));
                w0_.y = hu(__floats2half2_rn(o0[2] * r0, o0[3] * r0));
                w0_.z = hu(__floats2half2_rn(o0[4] * r0, o0[5] * r0));
                w0_.w = hu(__floats2half2_rn(o0[6] * r0, o0[7] * r0));
                w1_.x = hu(__floats2half2_rn(o1[0] * r1, o1[1] * r1));
                w1_.y = hu(__floats2half2_rn(o1[2] * r1, o1[3] * r1));
                w1_.z = hu(__floats2half2_rn(o1[4] * r1, o1[5] * r1));
                w1_.w = hu(__floats2half2_rn(o1[6] * r1, o1[7] * r1));
                w2_.x = hu(__floats2half2_rn(o2[0] * r2, o2[1] * r2));
                w2_.y = hu(__floats2half2_rn(o2[2] * r2, o2[3] * r2));
                w2_.z = hu(__floats2half2_rn(o2[4] * r2, o2[5] * r2));
                w2_.w = hu(__floats2half2_rn(o2[6] * r2, o2[7] * r2));
                orow[q] = w0_;
                orow[q + 8] = w1_;
                orow[q + 16] = w2_;
            }
        }
    }
}

// ---------------- GCN ----------------
__global__ void k_gcn1(const __half* __restrict__ h, const int* __restrict__ rp,
                       const int* __restrict__ col, float* __restrict__ out) {
    int t = blockIdx.x * blockDim.x + threadIdx.x;
    int wv = t >> 6, lane = t & 63, nw = (gridDim.x * blockDim.x) >> 6;
    int g = lane >> 3, q = lane & 7;
    const __half2 z = __floats2half2_rn(0.f, 0.f);
    for (int w0 = wv; w0 < NN; w0 += nw) {
        int n = nodeperm(w0);
        int e0 = rp[n], e1 = rp[n + 1];
        __half2 a[4] = {z, z, z, z};
        for (int eb = e0 + g; eb < e1; eb += 8) {
            int sn = col[eb];
            uint4 v = ((const uint4*)(h + (size_t)sn * DD))[q];
            a[0] = __hadd2(a[0], uh(v.x));
            a[1] = __hadd2(a[1], uh(v.y));
            a[2] = __hadd2(a[2], uh(v.z));
            a[3] = __hadd2(a[3], uh(v.w));
        }
#pragma unroll
        for (int j = 0; j < 4; j++) a[j] = h2rx(h2rx(h2rx(a[j], 8), 16), 32);
        if (g == 0) {
            float o[8];
#pragma unroll
            for (int j = 0; j < 4; j++) {
                float2 f = __half22float2(a[j]);
                o[2 * j] = f.x > 0.f ? f.x : 0.01f * f.x;
                o[2 * j + 1] = f.y > 0.f ? f.y : 0.01f * f.y;
            }
            float* ob = out + (size_t)n * DD + q * 8;
            *(float4*)(ob) = make_float4(o[0], o[1], o[2], o[3]);
            *(float4*)(ob + 4) = make_float4(o[4], o[5], o[6], o[7]);
        }
    }
}

__global__ void k_gcn_final2(const __half* __restrict__ gp, const int* __restrict__ rp,
                             const int* __restrict__ col, const float* __restrict__ x0,
                             const float* __restrict__ h1, float* __restrict__ out) {
    int t = blockIdx.x * blockDim.x + threadIdx.x;
    int wv = t >> 6, lane = t & 63, nw = (gridDim.x * blockDim.x) >> 6;
    int g = lane >> 3, q = lane & 7;
    const __half2 z = __floats2half2_rn(0.f, 0.f);
    for (int w0 = wv; w0 < NN; w0 += nw) {
        int n = nodeperm(w0);
        int e0 = rp[n], e1 = rp[n + 1];
        __half2 aA[4] = {z, z, z, z}, aB[4] = {z, z, z, z};
        for (int eb = e0 + g; eb < e1; eb += 8) {
            int sn = col[eb];
            const uint4* base = (const uint4*)(gp + (size_t)sn * 128);
            uint4 vA = base[q], vB = base[q + 8];
            aA[0] = __hadd2(aA[0], uh(vA.x));
            aA[1] = __hadd2(aA[1], uh(vA.y));
            aA[2] = __hadd2(aA[2], uh(vA.z));
            aA[3] = __hadd2(aA[3], uh(vA.w));
            aB[0] = __hadd2(aB[0], uh(vB.x));
            aB[1] = __hadd2(aB[1], uh(vB.y));
            aB[2] = __hadd2(aB[2], uh(vB.z));
            aB[3] = __hadd2(aB[3], uh(vB.w));
        }
#pragma unroll
        for (int j = 0; j < 4; j++) {
            aA[j] = h2rx(h2rx(h2rx(aA[j], 8), 16), 32);
            aB[j] = h2rx(h2rx(h2rx(aB[j], 8), 16), 32);
        }
        if (g == 0) {
            const float* p0 = x0 + (size_t)n * DD + q * 8;
            const float* p1 = h1 + (size_t)n * DD + q * 8;
            float4 v0a = *(const float4*)(p0), v0b = *(const float4*)(p0 + 4);
            float4 v1a = *(const float4*)(p1), v1b = *(const float4*)(p1 + 4);
            float o[8];
#pragma unroll
            for (int j = 0; j < 4; j++) {
                float2 fA = __half22float2(aA[j]);
                float2 fB = __half22float2(aB[j]);
                float h2x = fA.x > 0.f ? fA.x : 0.01f * fA.x;
                float h2y = fA.y > 0.f ? fA.y : 0.01f * fA.y;
                o[2 * j] = h2x + fB.x;
                o[2 * j + 1] = h2y + fB.y;
            }
            float* ob = out + (size_t)n * 256 + q * 8;
            *(float4*)(ob) = make_float4(o[0] + v0a.x + v1a.x, o[1] + v0a.y + v1a.y,
                                         o[2] + v0a.z + v1a.z, o[3] + v0a.w + v1a.w);
            *(float4*)(ob + 4) = make_float4(o[4] + v0b.x + v1b.x, o[5] + v0b.y + v1b.y,
                                             o[6] + v0b.z + v1b.z, o[7] + v0b.w + v1b.w);
        }
    }
}

extern "C" void kernel_launch(void* const* d_in, const int* in_sizes, int n_in,
                              void* d_out, int out_size, void* d_ws, size_t ws_size,
                              hipStream_t stream) {
    const int* ei       = (const int*)d_in[0];
    const float* v_feat = (const float*)d_in[1];
    const float* a_feat = (const float*)d_in[2];
    const float* t_feat = (const float*)d_in[3];
    const float* pref_v = (const float*)d_in[4];
    const float* pref_a = (const float*)d_in[5];
    const float* pref_t = (const float*)d_in[6];
    const float* mlp_v_w = (const float*)d_in[7];
    const float* mlp_v_b = (const float*)d_in[8];
    const float* mlp_a_w = (const float*)d_in[9];
    const float* mlp_a_b = (const float*)d_in[10];
    const float* mlp_t_w = (const float*)d_in[11];
    const float* mlp_t_b = (const float*)d_in[12];
    const float* pre_w  = (const float*)d_in[13];
    const float* ori_w  = (const float*)d_in[14];
    const float* gcn_w  = (const float*)d_in[15];
    const float* id_emb = (const float*)d_in[16];
    float* out = (float*)d_out;

    const int E2 = in_sizes[0];
    const int E  = E2 / 2;

    char* w = (char*)d_ws;
    auto alloc = [&](size_t bytes) -> void* {
        void* p = (void*)w;
        w += (bytes + 255) & ~(size_t)255;
        return p;
    };
    int* cnt  = (int*)alloc((size_t)NN * 4);
    int* rp   = (int*)alloc((size_t)(NN + 1) * 4);
    int* bsum = (int*)alloc(256);
    int* col  = (int*)alloc((size_t)E2 * 4);
    int* posw = (int*)alloc((size_t)E2 * 4);
    __half* Mh3  = (__half*)alloc(3 * PLANE * 2);
    __half* hb3h = (__half*)alloc(3 * PLANE * 2);
    __half* x3h  = (__half*)alloc(3 * PLANE * 2);
    __half* gf4  = (__half*)alloc((size_t)E2 * 4 * 2);
    float* x0f = (float*)alloc(PLANE * 4);
    float* h1f = (float*)alloc(PLANE * 4);

    __half* g1 = hb3h;
    __half* gpair = hb3h + PLANE;

    // ---- CSR by destination (hist records intra-bucket position; scatter atomic-free) ----
    const int NBLK = 64, CHUNK = (NN + NBLK - 1) / NBLK;
    hipMemsetAsync(cnt, 0, (size_t)NN * 4, stream);
    k_hist<<<(E2 + 255) / 256, 256, 0, stream>>>(ei, E2, E, cnt, posw);
    k_bsum<<<NBLK, 256, 0, stream>>>(cnt, bsum, NN, CHUNK);
    k_bscan<<<1, 64, 0, stream>>>(bsum, NBLK, rp + NN);
    k_apply<<<NBLK, 256, 0, stream>>>(cnt, bsum, rp, NN, CHUNK);
    k_scatter<<<(E2 + 255) / 256, 256, 0, stream>>>(ei, E2, E, rp, posw, col);

    // ---- node tables (interleaved fp16) ----
    k_prep_pref<<<640, 256, 0, stream>>>(pref_v, pref_a, pref_t, Mh3);
    k_mlp<128><<<1024, 256, 0, stream>>>(v_feat, mlp_v_w, mlp_v_b, Mh3, 0);
    k_mlp<128><<<1024, 256, 0, stream>>>(a_feat, mlp_a_w, mlp_a_b, Mh3, 1);
    k_mlp<100><<<1024, 256, 0, stream>>>(t_feat, mlp_t_w, mlp_t_b, Mh3, 2);

    const int GB = (NN + 3) / 4;

    // ---- cross-modal gates ----
    k_edgedot3<<<GB, 256, 0, stream>>>(Mh3, rp, col, gf4);

    // ---- 3-modality chains (MFMA gemms) ----
    dim3 gm(640, 3);
    k_gemm_mfma<<<gm, 256, 0, stream>>>(Mh3, pre_w, hb3h);
    k_gat_pre3<<<GB, 256, 0, stream>>>(hb3h, gf4, rp, col, x3h);
    for (int it = 0; it < 3; it++) {
        k_gemm_mfma<<<gm, 256, 0, stream>>>(x3h, ori_w, hb3h);
        if (it < 2)
            k_gat_ori3<<<GB, 256, 0, stream>>>(hb3h, x3h, rp, col, x3h, nullptr);
        else
            k_gat_ori3<<<GB, 256, 0, stream>>>(hb3h, x3h, rp, col, nullptr, out);
    }

    // ---- real_gcn ----
    k_gemm_id<<<1280, 256, 0, stream>>>(id_emb, gcn_w, g1, x0f);
    k_gcn1<<<GB, 256, 0, stream>>>(g1, rp, col, h1f);
    dim3 g2(1280, 2);
    k_gemm_f2<<<g2, 256, 0, stream>>>(h1f, gcn_w + 4096, gpair);
    k_gcn_final2<<<GB, 256, 0, stream>>>(gpair, rp, col, x0f, h1f, out);
}